// Round 5
// baseline (981.209 us; speedup 1.0000x reference)
//
#include <hip/hip_runtime.h>
#include <math.h>

#define B  8
#define T  200
#define U  100
#define U1 101
#define V  1024
#define NROWS (B * T * U1)   // 161600

typedef float f4 __attribute__((ext_vector_type(4)));

// ---------------------------------------------------------------------------
// Kernel 1: per (b,t,u) row of V=1024 logits, compute logsumexp and emit only
// the two needed log-probs. One wave per row, 16 floats/lane via 4x float4
// nontemporal loads (read-once stream; keep L2 clean for kernel 2).
// Rows with t >= logit_len[b] or u > tgt_len[b] are skipped entirely
// (they cannot influence alpha[t_last][tl]) -> ~34% less HBM traffic.
// Blank/target logits extracted from registers via shuffle (no re-read).
// __expf (v_exp_f32) instead of libm expf: 16 precise expf/lane would make
// the kernel VALU-bound (~580 cyc/wave) vs ~410 cyc of HBM time.
// ---------------------------------------------------------------------------
__global__ __launch_bounds__(256) void rnnt_row_lse(
    const float* __restrict__ logits,
    const int*   __restrict__ targets,
    const int*   __restrict__ logit_lengths,
    const int*   __restrict__ target_lengths,
    float*       __restrict__ blank_lp,
    float*       __restrict__ emit_lp)
{
    const int wave = threadIdx.x >> 6;
    const int lane = threadIdx.x & 63;
    const int row  = blockIdx.x * 4 + wave;
    if (row >= NROWS) return;

    const int b   = row / (T * U1);
    const int rem = row - b * (T * U1);
    const int t   = rem / U1;
    const int u   = rem - t * U1;

    // wave-uniform early exit: this row can never reach the output cell
    if (t >= logit_lengths[b] || u > target_lengths[b]) return;

    const f4* rp4 = (const f4*)(logits + (long long)row * V);

    f4 v0 = __builtin_nontemporal_load(rp4 + lane);
    f4 v1 = __builtin_nontemporal_load(rp4 + lane + 64);
    f4 v2 = __builtin_nontemporal_load(rp4 + lane + 128);
    f4 v3 = __builtin_nontemporal_load(rp4 + lane + 192);

    float m = fmaxf(fmaxf(fmaxf(v0.x, v0.y), fmaxf(v0.z, v0.w)),
                    fmaxf(fmaxf(v1.x, v1.y), fmaxf(v1.z, v1.w)));
    m = fmaxf(m, fmaxf(fmaxf(fmaxf(v2.x, v2.y), fmaxf(v2.z, v2.w)),
                       fmaxf(fmaxf(v3.x, v3.y), fmaxf(v3.z, v3.w))));
    #pragma unroll
    for (int mask = 32; mask >= 1; mask >>= 1)
        m = fmaxf(m, __shfl_xor(m, mask, 64));

    float s = __expf(v0.x - m) + __expf(v0.y - m) + __expf(v0.z - m) + __expf(v0.w - m)
            + __expf(v1.x - m) + __expf(v1.y - m) + __expf(v1.z - m) + __expf(v1.w - m)
            + __expf(v2.x - m) + __expf(v2.y - m) + __expf(v2.z - m) + __expf(v2.w - m)
            + __expf(v3.x - m) + __expf(v3.y - m) + __expf(v3.z - m) + __expf(v3.w - m);
    #pragma unroll
    for (int mask = 32; mask >= 1; mask >>= 1)
        s += __shfl_xor(s, mask, 64);

    const float lse = m + logf(s);

    // blank logit = element V-1 = v3.w of lane 63
    const float blank_logit = __shfl(v3.w, 63, 64);

    float emit_logit = 0.f;
    const int has_emit = (u < U);          // wave-uniform
    if (has_emit) {
        const int tgt = targets[b * U + u];            // wave-uniform load
        const int k  = tgt >> 8;                       // which float4 chunk
        const int ls = (tgt >> 2) & 63;                // which lane in chunk
        const int c  = tgt & 3;                        // which component
        f4 vk = (k == 0) ? v0 : (k == 1) ? v1 : (k == 2) ? v2 : v3;
        float comp = (c == 0) ? vk.x : (c == 1) ? vk.y : (c == 2) ? vk.z : vk.w;
        emit_logit = __shfl(comp, ls, 64);
    }

    if (lane == 0) {
        blank_lp[row] = blank_logit - lse;
        if (has_emit)
            emit_lp[(b * T + t) * U + u] = emit_logit - lse;
    }
}

// ---------------------------------------------------------------------------
// Kernel 2: alpha forward recursion, ONE WAVE per batch element.
// Lane l owns columns u=l and u=l+64. Anti-diagonal wavefront; the left
// parent (t, u-1) lives on lane l-1 and is fetched with a register shuffle —
// no LDS, no __syncthreads, so the compiler never drains vmcnt and the
// global-load pipeline (2 diagonals deep, alternating A/B register sets)
// actually stays in flight across iterations.
//   alpha[0][0] = 0
//   alpha[t][u] = logaddexp(alpha[t-1][u] + blank[t-1][u],
//                           alpha[t][u-1] + emit [t][u-1])
//   cost = -(alpha[t_last][tl] + blank[t_last][tl])
// Only the sub-lattice t <= t_last, u <= tl is computed/loaded (matches the
// region kernel 1 initializes).
// ---------------------------------------------------------------------------
__global__ __launch_bounds__(64) void rnnt_alpha(
    const float* __restrict__ blank_lp,
    const float* __restrict__ emit_lp,
    const int*   __restrict__ logit_lengths,
    const int*   __restrict__ target_lengths,
    float*       __restrict__ out)
{
    const int b      = blockIdx.x;
    const int lane   = threadIdx.x;        // 0..63
    const int u0     = lane;
    const int u1c    = lane + 64;
    const int lanem1 = (lane + 63) & 63;
    const int t_last = logit_lengths[b] - 1;
    const int tl     = target_lengths[b];

    const float* blp = blank_lp + b * (T * U1);
    const float* elp = emit_lp  + b * (T * U);

    const float final_blank = blp[t_last * U1 + tl];

    float a0 = -INFINITY;   // alpha on previous diagonal, column u0
    float a1 = -INFINITY;   // alpha on previous diagonal, column u1c

#define LOADS(dd, bl0, em0, bl1, em1)                                          \
    {                                                                          \
        const int t0 = (dd) - u0;                                              \
        const int t1 = (dd) - u1c;                                             \
        bl0 = (u0 <= tl && t0 >= 1 && t0 <= t_last)                            \
                  ? blp[(t0 - 1) * U1 + u0] : 0.f;                             \
        em0 = (u0 >= 1 && u0 <= tl && t0 >= 0 && t0 <= t_last)                 \
                  ? elp[t0 * U + (u0 - 1)] : 0.f;                              \
        bl1 = (u1c <= tl && t1 >= 1 && t1 <= t_last)                           \
                  ? blp[(t1 - 1) * U1 + u1c] : 0.f;                            \
        em1 = (u1c <= tl && t1 >= 0 && t1 <= t_last)                           \
                  ? elp[t1 * U + (u1c - 1)] : 0.f;                             \
    }

#define STEP(dd, bl0, em0, bl1, em1)                                           \
    {                                                                          \
        const float r0 = __shfl(a0, lanem1, 64);  /* col u-1's alpha */        \
        const float r1 = __shfl(a1, lanem1, 64);                               \
        const int t0 = (dd) - u0;                                              \
        const int t1 = (dd) - u1c;                                             \
        if (u0 <= tl && t0 >= 0 && t0 <= t_last) {                             \
            const float top  = (t0 > 0) ? a0 + (bl0) : -INFINITY;              \
            const float left = (u0 > 0) ? r0 + (em0) : -INFINITY;              \
            const float mx = fmaxf(top, left);                                 \
            const float mn = fminf(top, left);                                 \
            const float av = ((dd) == 0) ? 0.f                                 \
                                         : mx + log1pf(__expf(mn - mx));       \
            a0 = av;                                                           \
            if (t0 == t_last && u0 == tl) out[b] = -(av + final_blank);        \
        }                                                                      \
        if (u1c <= tl && t1 >= 0 && t1 <= t_last) {                            \
            /* left parent of u=64 (lane 0) is column 63 = lane 63's slot0 */  \
            const float leftv = (lane == 0) ? r0 : r1;                         \
            const float top  = (t1 > 0) ? a1 + (bl1) : -INFINITY;              \
            const float left = leftv + (em1);      /* u1c >= 64 > 0 always */  \
            const float mx = fmaxf(top, left);                                 \
            const float mn = fminf(top, left);                                 \
            const float av = mx + log1pf(__expf(mn - mx));                     \
            a1 = av;                                                           \
            if (t1 == t_last && u1c == tl) out[b] = -(av + final_blank);       \
        }                                                                      \
    }

    float blA0, emA0, blA1, emA1;
    float blB0, emB0, blB1, emB1;
    LOADS(0, blA0, emA0, blA1, emA1);      // diag 0 (all guarded to 0)
    LOADS(1, blB0, emB0, blB1, emB1);      // diag 1 in flight

    const int dmax = t_last + tl;          // last diagonal that matters
    for (int d = 0; d <= dmax; d += 2) {
        STEP(d,      blA0, emA0, blA1, emA1);   // consume A (loaded 1 iter ago)
        LOADS(d + 2, blA0, emA0, blA1, emA1);   // refill A, 2 phases of flight
        STEP(d + 1,  blB0, emB0, blB1, emB1);   // consume B
        LOADS(d + 3, blB0, emB0, blB1, emB1);   // refill B
    }
#undef LOADS
#undef STEP
}

extern "C" void kernel_launch(void* const* d_in, const int* in_sizes, int n_in,
                              void* d_out, int out_size, void* d_ws, size_t ws_size,
                              hipStream_t stream) {
    const float* logits         = (const float*)d_in[0];
    const int*   targets        = (const int*)d_in[1];
    const int*   logit_lengths  = (const int*)d_in[2];
    const int*   target_lengths = (const int*)d_in[3];
    float*       out            = (float*)d_out;

    float* blank_lp = (float*)d_ws;                  // B*T*U1 floats
    float* emit_lp  = blank_lp + (size_t)B * T * U1; // B*T*U floats

    const int rows_per_block = 4;   // 4 waves/block, 1 row/wave
    const int grid1 = (NROWS + rows_per_block - 1) / rows_per_block;
    rnnt_row_lse<<<grid1, 256, 0, stream>>>(logits, targets,
                                            logit_lengths, target_lengths,
                                            blank_lp, emit_lp);

    rnnt_alpha<<<B, 64, 0, stream>>>(blank_lp, emit_lp,
                                     logit_lengths, target_lengths, out);
}